// Round 2
// baseline (191.369 us; speedup 1.0000x reference)
//
#include <hip/hip_runtime.h>
#include <math.h>

#define B 4
#define P 19248
#define C 81
#define M 32
#define K1 100
#define K2 15
#define G 32
#define HP 138
#define HO 550
#define FEPS 1e-6f
#define NLOC 19   // ceil(P/1024)

#define NBUCKET 8192   // bits >> 17; conf1 in (0,1) -> bucket < 8128
#define CAP 2048       // candidate cap

// iou tiling
#define TI 16          // gaussians per tile
#define NT 7           // ceil(112/16) tiles covering K1=100
#define NTP 28         // tile pairs ti<=tj
#define CH 128         // pixels per chunk
#define NCH 8          // 1024/CH
#define SP 132         // padded LDS row stride (floats): 528B/row, 16B-aligned,
                       // 132%32=4 banks/row skew -> 2-way max conflict (free, m136)

// ---------------- Stage 1: conf1 = softmax(conf, axis=2)[:, :, 1] ----------
// Block 0 additionally zeroes ioumax and d_out (stream-ordered before their
// consumers) -- keeps the pipeline memset-free.
__global__ void k_conf1(const float* __restrict__ conf, float* __restrict__ conf1,
                        unsigned int* __restrict__ ioumax, float* __restrict__ out) {
    if (blockIdx.x == 0) {
        for (int t = threadIdx.x; t < B * K1; t += 256) ioumax[t] = 0u;
        if (threadIdx.x == 0) out[0] = 0.f;
    }
    int gid  = blockIdx.x * blockDim.x + threadIdx.x;
    int wave = gid >> 6;
    int lane = threadIdx.x & 63;
    if (wave >= B * P) return;
    const float* row = conf + (size_t)wave * C;
    float x0 = (lane < C)      ? row[lane]      : -INFINITY;
    float x1 = (lane + 64 < C) ? row[lane + 64] : -INFINITY;
    float m = fmaxf(x0, x1);
#pragma unroll
    for (int o = 32; o; o >>= 1) m = fmaxf(m, __shfl_xor(m, o, 64));
    float s = 0.f;
    if (lane < C)      s += expf(x0 - m);
    if (lane + 64 < C) s += expf(x1 - m);
#pragma unroll
    for (int o = 32; o; o >>= 1) s += __shfl_xor(s, o, 64);
    if (lane == 0) conf1[wave] = expf(row[1] - m) / s;
}

// ---------------- Stage 2: top-100 by conf1 via radix-histogram select -----
__global__ __launch_bounds__(1024) void k_top100(
    const float* __restrict__ conf1, const float* __restrict__ loc,
    const float* __restrict__ mask,
    float* __restrict__ sconf, float* __restrict__ sloc,
    float* __restrict__ smask) {
    int b = blockIdx.x;
    int tid = threadIdx.x;
    const float* c1 = conf1 + (size_t)b * P;

    __shared__ unsigned int hist[NBUCKET];
    __shared__ unsigned int gsum_[1024];
    __shared__ unsigned int g2[64];
    __shared__ unsigned long long keys[CAP];
    __shared__ int s_T;
    __shared__ int s_cnt;
    __shared__ int   s_order[K1];
    __shared__ float s_conf[K1];

    for (int i = tid; i < NBUCKET; i += 1024) hist[i] = 0;
    if (tid == 0) s_cnt = 0;
    __syncthreads();

    unsigned int mybits[NLOC];
#pragma unroll
    for (int s = 0; s < NLOC; ++s) {
        int p = tid + s * 1024;
        mybits[s] = (p < P) ? __float_as_uint(c1[p]) : 0u;
        if (p < P) atomicAdd(&hist[mybits[s] >> 17], 1u);
    }
    __syncthreads();

    {
        unsigned int gs = 0;
#pragma unroll
        for (int i = 0; i < 8; ++i) gs += hist[tid * 8 + i];
        gsum_[tid] = gs;
    }
    __syncthreads();
    if (tid < 64) {
        unsigned int gs = 0;
#pragma unroll
        for (int i = 0; i < 16; ++i) gs += gsum_[tid * 16 + i];
        g2[tid] = gs;
    }
    __syncthreads();

    if (tid == 0) {
        int cum = 0;
        int S = 63;
        for (; S > 0; --S) {
            if (cum + (int)g2[S] >= K1) break;
            cum += (int)g2[S];
        }
        int gI = S * 16 + 15;
        for (; gI > S * 16; --gI) {
            if (cum + (int)gsum_[gI] >= K1) break;
            cum += (int)gsum_[gI];
        }
        int T = gI * 8 + 7;
        for (; T > gI * 8; --T) {
            cum += (int)hist[T];
            if (cum >= K1) break;
        }
        s_T = T;
    }
    __syncthreads();

    int T = s_T;
#pragma unroll
    for (int s = 0; s < NLOC; ++s) {
        int p = tid + s * 1024;
        if (p < P && (int)(mybits[s] >> 17) >= T) {
            int pos = atomicAdd(&s_cnt, 1);
            if (pos < CAP)
                keys[pos] = ((unsigned long long)mybits[s] << 32)
                          | (unsigned int)(0xFFFFFFFFu - (unsigned int)p);
        }
    }
    __syncthreads();
    int nc = min(s_cnt, CAP);

    if (tid < nc) {
        unsigned long long mk = keys[tid];
        int rank = 0;
        for (int i = 0; i < nc; ++i) rank += (keys[i] > mk);
        if (rank < K1) {
            unsigned int bits = (unsigned int)(mk >> 32);
            int idx = (int)(0xFFFFFFFFu - (unsigned int)(mk & 0xFFFFFFFFu));
            s_order[rank] = idx;
            s_conf[rank] = __uint_as_float(bits);
        }
    }
    __syncthreads();

    for (int t = tid; t < K1; t += 1024) {
        sconf[b * K1 + t] = s_conf[t];
    }
    for (int t = tid; t < K1 * 4; t += 1024) {
        int k = t >> 2, d = t & 3;
        sloc[(b * K1 + k) * 4 + d] = loc[((size_t)b * P + s_order[k]) * 4 + d];
    }
    for (int t = tid; t < K1 * M; t += 1024) {
        int k = t >> 5, d = t & 31;
        smask[(b * K1 + k) * M + d] = mask[((size_t)b * P + s_order[k]) * M + d];
    }
}

// ---------------- Stage 3: fused gauss + inter/union + iou + atomicMax -----
// One block per (tilepair, b). Gaussian values are computed INLINE into LDS
// (identical arithmetic to the old k_gauss, so the sums are bit-identical)
// -- removes the k_gauss dispatch and the gauss global buffer entirely.
// Each pair's inter/union completes in registers -> single atomicMax.
// DIRECT min/max sums (no (S-D)/(S+D) identity -- that cancellation flipped
// the rank-15 selection for near-disjoint pairs in a previous round).
__global__ __launch_bounds__(256) void k_iou(
    const float* __restrict__ sloc, unsigned int* __restrict__ ioumax) {
    int tp = blockIdx.x;
    int b  = blockIdx.y;
    int ti = 0, rem = tp;
    while (rem >= NT - ti) { rem -= NT - ti; ++ti; }
    int tj = ti + rem;

    __shared__ __align__(16) float As[TI][SP];
    __shared__ __align__(16) float Bs[TI][SP];
    __shared__ float pa[2][TI][4];   // cx, cy, 2sx^2, 2sy^2 per row

    int tid = threadIdx.x;
    if (tid < 2 * TI) {
        int which = tid >> 4, g = tid & 15;
        int gi = (which ? tj : ti) * TI + g;
        float cx = 0.f, cy = 0.f, dsx = 1.f, dsy = 1.f;
        if (gi < K1) {
            const float* l = sloc + (size_t)(b * K1 + gi) * 4;
            cx = l[0]; cy = l[1];
            float sx = fabsf(l[2]) * 0.5f + 0.001f;
            float sy = fabsf(l[3]) * 0.5f + 0.001f;
            dsx = 2.f * sx * sx;
            dsy = 2.f * sy * sy;
        }
        pa[which][g][0] = cx; pa[which][g][1] = cy;
        pa[which][g][2] = dsx; pa[which][g][3] = dsy;
    }
    // (first __syncthreads of the chunk loop covers pa visibility)

    int li = tid >> 4, lj = tid & 15;
    int i = ti * TI + li, j = tj * TI + lj;

    float inter = 0.f, uni = 0.f;
    for (int ch = 0; ch < NCH; ++ch) {
        __syncthreads();   // prior chunk's reads done before overwrite (+pa ready)
        // compute 16 rows x 128 px for each of As, Bs: 8 values/thread/array
#pragma unroll
        for (int t = 0; t < TI * CH / 256; ++t) {
            int idx = tid + t * 256;
            int g = idx >> 7, px = idx & 127;
            int p = ch * CH + px;
            int y = p >> 5, x = p & 31;
            float xs = (x + 0.5f) / (float)G;
            float ys = (y + 0.5f) / (float)G;
            {
                float cx = pa[0][g][0], cy = pa[0][g][1];
                float dx2 = (xs - cx) * (xs - cx) / pa[0][g][2];
                float dy2 = (ys - cy) * (ys - cy) / pa[0][g][3];
                As[g][px] = expf(-(dy2 + dx2));
            }
            {
                float cx = pa[1][g][0], cy = pa[1][g][1];
                float dx2 = (xs - cx) * (xs - cx) / pa[1][g][2];
                float dy2 = (ys - cy) * (ys - cy) / pa[1][g][3];
                Bs[g][px] = expf(-(dy2 + dx2));
            }
        }
        __syncthreads();
        const float4* ar = (const float4*)(&As[li][0]);
        const float4* br = (const float4*)(&Bs[lj][0]);
#pragma unroll
        for (int p = 0; p < CH / 4; ++p) {
            float4 a = ar[p], c = br[p];
            inter += fminf(a.x, c.x) + fminf(a.y, c.y)
                   + fminf(a.z, c.z) + fminf(a.w, c.w);
            uni   += fmaxf(a.x, c.x) + fmaxf(a.y, c.y)
                   + fmaxf(a.z, c.z) + fmaxf(a.w, c.w);
        }
    }
    if (i < j && j < K1) {
        float iou = inter / uni;   // > 0, so uint-compare == float-compare
        atomicMax(&ioumax[b * K1 + j], __float_as_uint(iou));
    }
}

// ---------------- Stage 4: keep-select + final_conf at 138x138 -------------
// Each block redundantly redoes the 15-smallest-iou_max selection (wave 0,
// ~700 cycles) and gathers kmask/kloc/kconf straight from smask/sloc/sconf
// -- removes the k_keep dispatch and its buffers.
__global__ __launch_bounds__(256) void k_fconf(
    const float* __restrict__ proto, const unsigned int* __restrict__ ioumax,
    const float* __restrict__ sloc, const float* __restrict__ smask,
    const float* __restrict__ sconf, float* __restrict__ fconf) {
    int b = blockIdx.y;
    int px0 = blockIdx.x * 256;
    int tid = threadIdx.x;
    __shared__ float s_pv[256][M + 1];
    __shared__ float s_km[K2][M];
    __shared__ float s_loc[K2][4];
    __shared__ float s_cf[K2];
    __shared__ int s_keep[K2];

    if (tid < 64) {   // wave 0: stable 15-smallest selection
        int lane = tid;
        float v0 = (lane < K1)      ? __uint_as_float(ioumax[b * K1 + lane])      : INFINITY;
        float v1 = (lane + 64 < K1) ? __uint_as_float(ioumax[b * K1 + lane + 64]) : INFINITY;
        for (int k = 0; k < K2; ++k) {
            float bv; int bi;
            if (v0 <= v1) { bv = v0; bi = lane; }
            else          { bv = v1; bi = lane + 64; }
#pragma unroll
            for (int o = 32; o; o >>= 1) {
                float ov = __shfl_xor(bv, o, 64);
                int   oi = __shfl_xor(bi, o, 64);
                if (ov < bv || (ov == bv && oi < bi)) { bv = ov; bi = oi; }
            }
            if (bi == lane)           v0 = INFINITY;
            else if (bi == lane + 64) v1 = INFINITY;
            if (lane == 0) s_keep[k] = bi;
        }
    }
    __syncthreads();

    for (int t = tid; t < K2 * M; t += 256) {
        int k = t >> 5, d = t & 31;
        s_km[k][d] = smask[(b * K1 + s_keep[k]) * M + d];
    }
    for (int t = tid; t < K2 * 4; t += 256) {
        int k = t >> 2, d = t & 3;
        s_loc[k][d] = sloc[(b * K1 + s_keep[k]) * 4 + d];
    }
    if (tid < K2) s_cf[tid] = sconf[b * K1 + s_keep[tid]];

    int nvalid = min(256, HP * HP - px0);
    const float4* pr4 = (const float4*)(proto + ((size_t)b * (HP * HP) + px0) * M);
    for (int idx = tid; idx < nvalid * (M / 4); idx += 256) {
        float4 f = pr4[idx];
        int q = idx >> 3, v = idx & 7;
        s_pv[q][v * 4 + 0] = f.x;
        s_pv[q][v * 4 + 1] = f.y;
        s_pv[q][v * 4 + 2] = f.z;
        s_pv[q][v * 4 + 3] = f.w;
    }
    __syncthreads();

    if (tid < nvalid) {
        int p = px0 + tid;
        int h = p / HP, w = p % HP;
        float pv[M];
#pragma unroll
        for (int m = 0; m < M; ++m) pv[m] = s_pv[tid][m];
        float ys = (h + 0.5f) / (float)HP;
        float xs = (w + 0.5f) / (float)HP;
        float sum_a = 0.f, sum_a2 = 0.f;
#pragma unroll 1
        for (int k = 0; k < K2; ++k) {
            float d = 0.f;
#pragma unroll
            for (int m = 0; m < M; ++m) d += pv[m] * s_km[k][m];
            float sig = 1.f / (1.f + expf(-d));
            float cx = s_loc[k][0], cy = s_loc[k][1];
            float sx = fabsf(s_loc[k][2]) * 0.5f + 0.001f;
            float sy = fabsf(s_loc[k][3]) * 0.5f + 0.001f;
            float dx2 = (xs - cx) * (xs - cx) / (2.f * sx * sx);
            float dy2 = (ys - cy) * (ys - cy) / (2.f * sy * sy);
            float ug = expf(-(dy2 + dx2));
            float a = sig * ug * s_cf[k];
            sum_a  += a;
            sum_a2 += a * a;
        }
        float fin = 1.f - sum_a2 / (sum_a + FEPS);
        if (!(fin == fin)) fin = 0.f;
        fconf[(size_t)b * HP * HP + p] = fin;
    }
}

// ---------------- Stage 5: bilinear resize 138->550 fused with variance ----
// Accumulates directly into d_out (pre-zeroed by k_conf1) with /100 folded.
__global__ void k_reduce(const float* __restrict__ fconf, const float* __restrict__ original,
                         float* __restrict__ out) {
    int idx = blockIdx.x * 256 + threadIdx.x;
    float contrib = 0.f;
    if (idx < HO * HO) {
        int y = idx / HO, x = idx % HO;
        const float scale = (float)HP / (float)HO;
        float fy = (y + 0.5f) * scale - 0.5f;
        float fx = (x + 0.5f) * scale - 0.5f;
        float y0f = floorf(fy), x0f = floorf(fx);
        float wy = fy - y0f, wx = fx - x0f;
        int y0 = (int)y0f, x0 = (int)x0f;
        int iy0 = max(y0, 0), iy1 = min(y0 + 1, HP - 1);
        int ix0 = max(x0, 0), ix1 = min(x0 + 1, HP - 1);
        float r[B];
#pragma unroll
        for (int b = 0; b < B; ++b) {
            const float* F = fconf + (size_t)b * HP * HP;
            float v00 = F[iy0 * HP + ix0], v01 = F[iy0 * HP + ix1];
            float v10 = F[iy1 * HP + ix0], v11 = F[iy1 * HP + ix1];
            r[b] = (1.f - wy) * ((1.f - wx) * v00 + wx * v01)
                 +        wy  * ((1.f - wx) * v10 + wx * v11);
        }
        float t = r[0] + r[1] + r[2] + r[3];
        float s = 0.f;
#pragma unroll
        for (int c = 0; c < 3; ++c) {
            float o[B], wm = 0.f;
#pragma unroll
            for (int b = 0; b < B; ++b) {
                o[b] = original[(((size_t)b * 3 + c) * HO + y) * HO + x];
                wm += o[b] * r[b];
            }
#pragma unroll
            for (int b = 0; b < B; ++b) {
                float d = o[b] - wm;
                s += d * d * r[b];
            }
        }
        contrib = s / (t + FEPS);
    }
    __shared__ float red[256];
    red[threadIdx.x] = contrib;
    __syncthreads();
    for (int off = 128; off; off >>= 1) {
        if (threadIdx.x < off) red[threadIdx.x] += red[threadIdx.x + off];
        __syncthreads();
    }
    if (threadIdx.x == 0) atomicAdd(out, red[0] * 0.01f);
}

extern "C" void kernel_launch(void* const* d_in, const int* in_sizes, int n_in,
                              void* d_out, int out_size, void* d_ws, size_t ws_size,
                              hipStream_t stream) {
    (void)in_sizes; (void)n_in; (void)out_size; (void)ws_size;
    const float* original = (const float*)d_in[0];
    const float* loc      = (const float*)d_in[1];
    const float* conf     = (const float*)d_in[2];
    const float* mask     = (const float*)d_in[3];
    const float* proto    = (const float*)d_in[4];
    float* out = (float*)d_out;

    char* ws = (char*)d_ws;
    size_t off = 0;
    auto alloc = [&](size_t bytes) -> void* {
        void* p = ws + off;
        off += (bytes + 255) & ~(size_t)255;
        return p;
    };
    float* conf1        = (float*)alloc((size_t)B * P * sizeof(float));
    float* sconf        = (float*)alloc((size_t)B * K1 * sizeof(float));
    float* sloc         = (float*)alloc((size_t)B * K1 * 4 * sizeof(float));
    float* smask        = (float*)alloc((size_t)B * K1 * M * sizeof(float));
    unsigned int* iomax = (unsigned int*)alloc((size_t)B * K1 * sizeof(unsigned int));
    float* fconf        = (float*)alloc((size_t)B * HP * HP * sizeof(float));

    // 5 dispatches (was 7; originally 9 kernels + 4 memsets):
    k_conf1<<<(B * P) / 4, 256, 0, stream>>>(conf, conf1, iomax, out);
    k_top100<<<B, 1024, 0, stream>>>(conf1, loc, mask, sconf, sloc, smask);
    dim3 g4(NTP, B);
    k_iou<<<g4, 256, 0, stream>>>(sloc, iomax);
    dim3 g6((HP * HP + 255) / 256, B);
    k_fconf<<<g6, 256, 0, stream>>>(proto, iomax, sloc, smask, sconf, fconf);
    k_reduce<<<(HO * HO + 255) / 256, 256, 0, stream>>>(fconf, original, out);
}

// Round 3
// 167.337 us; speedup vs baseline: 1.1436x; 1.1436x over previous
//
#include <hip/hip_runtime.h>
#include <math.h>

#define B 4
#define P 19248
#define C 81
#define M 32
#define K1 100
#define K2 15
#define G 32
#define HP 138
#define HO 550
#define FEPS 1e-6f
#define NLOC 19   // ceil(P/1024)

#define NBUCKET 8192   // bits >> 17; conf1 in (0,1) -> bucket < 8128
#define CAP 2048       // candidate cap

// iou tiling -- chunk-PARALLEL (R0 shape: 28 tilepairs x 8 chunks x 4 b = 896
// blocks). R1/R2 serialized chunks into 112 blocks -> 4% occupancy, k_iou
// ballooned to 55.6 us (latency-bound, VALUBusy 12%). Parallelism > fewer
// dispatches here.
#define TI 16          // gaussians per tile
#define NT 7           // ceil(112/16) tiles covering K1=100
#define NTP 28         // tile pairs ti<=tj
#define CH 128         // pixels per chunk
#define NCH 8          // 1024/CH
#define SP 132         // padded LDS row stride (floats): 528B/row, 16B-aligned

// ---------------- Stage 1: conf1 = softmax(conf, axis=2)[:, :, 1] ----------
// Block 0 additionally zeroes ioumax and d_out (stream-ordered before their
// consumers) -- keeps the pipeline memset-free.
__global__ void k_conf1(const float* __restrict__ conf, float* __restrict__ conf1,
                        unsigned int* __restrict__ ioumax, float* __restrict__ out) {
    if (blockIdx.x == 0) {
        for (int t = threadIdx.x; t < B * K1; t += 256) ioumax[t] = 0u;
        if (threadIdx.x == 0) out[0] = 0.f;
    }
    int gid  = blockIdx.x * blockDim.x + threadIdx.x;
    int wave = gid >> 6;
    int lane = threadIdx.x & 63;
    if (wave >= B * P) return;
    const float* row = conf + (size_t)wave * C;
    float x0 = (lane < C)      ? row[lane]      : -INFINITY;
    float x1 = (lane + 64 < C) ? row[lane + 64] : -INFINITY;
    float m = fmaxf(x0, x1);
#pragma unroll
    for (int o = 32; o; o >>= 1) m = fmaxf(m, __shfl_xor(m, o, 64));
    float s = 0.f;
    if (lane < C)      s += expf(x0 - m);
    if (lane + 64 < C) s += expf(x1 - m);
#pragma unroll
    for (int o = 32; o; o >>= 1) s += __shfl_xor(s, o, 64);
    if (lane == 0) conf1[wave] = expf(row[1] - m) / s;
}

// ---------------- Stage 2: top-100 by conf1 via radix-histogram select -----
__global__ __launch_bounds__(1024) void k_top100(
    const float* __restrict__ conf1, const float* __restrict__ loc,
    const float* __restrict__ mask,
    float* __restrict__ sconf, float* __restrict__ sloc,
    float* __restrict__ smask) {
    int b = blockIdx.x;
    int tid = threadIdx.x;
    const float* c1 = conf1 + (size_t)b * P;

    __shared__ unsigned int hist[NBUCKET];
    __shared__ unsigned int gsum_[1024];
    __shared__ unsigned int g2[64];
    __shared__ unsigned long long keys[CAP];
    __shared__ int s_T;
    __shared__ int s_cnt;
    __shared__ int   s_order[K1];
    __shared__ float s_conf[K1];

    for (int i = tid; i < NBUCKET; i += 1024) hist[i] = 0;
    if (tid == 0) s_cnt = 0;
    __syncthreads();

    unsigned int mybits[NLOC];
#pragma unroll
    for (int s = 0; s < NLOC; ++s) {
        int p = tid + s * 1024;
        mybits[s] = (p < P) ? __float_as_uint(c1[p]) : 0u;
        if (p < P) atomicAdd(&hist[mybits[s] >> 17], 1u);
    }
    __syncthreads();

    {
        unsigned int gs = 0;
#pragma unroll
        for (int i = 0; i < 8; ++i) gs += hist[tid * 8 + i];
        gsum_[tid] = gs;
    }
    __syncthreads();
    if (tid < 64) {
        unsigned int gs = 0;
#pragma unroll
        for (int i = 0; i < 16; ++i) gs += gsum_[tid * 16 + i];
        g2[tid] = gs;
    }
    __syncthreads();

    if (tid == 0) {
        int cum = 0;
        int S = 63;
        for (; S > 0; --S) {
            if (cum + (int)g2[S] >= K1) break;
            cum += (int)g2[S];
        }
        int gI = S * 16 + 15;
        for (; gI > S * 16; --gI) {
            if (cum + (int)gsum_[gI] >= K1) break;
            cum += (int)gsum_[gI];
        }
        int T = gI * 8 + 7;
        for (; T > gI * 8; --T) {
            cum += (int)hist[T];
            if (cum >= K1) break;
        }
        s_T = T;
    }
    __syncthreads();

    int T = s_T;
#pragma unroll
    for (int s = 0; s < NLOC; ++s) {
        int p = tid + s * 1024;
        if (p < P && (int)(mybits[s] >> 17) >= T) {
            int pos = atomicAdd(&s_cnt, 1);
            if (pos < CAP)
                keys[pos] = ((unsigned long long)mybits[s] << 32)
                          | (unsigned int)(0xFFFFFFFFu - (unsigned int)p);
        }
    }
    __syncthreads();
    int nc = min(s_cnt, CAP);

    if (tid < nc) {
        unsigned long long mk = keys[tid];
        int rank = 0;
        for (int i = 0; i < nc; ++i) rank += (keys[i] > mk);
        if (rank < K1) {
            unsigned int bits = (unsigned int)(mk >> 32);
            int idx = (int)(0xFFFFFFFFu - (unsigned int)(mk & 0xFFFFFFFFu));
            s_order[rank] = idx;
            s_conf[rank] = __uint_as_float(bits);
        }
    }
    __syncthreads();

    for (int t = tid; t < K1; t += 1024) {
        sconf[b * K1 + t] = s_conf[t];
    }
    for (int t = tid; t < K1 * 4; t += 1024) {
        int k = t >> 2, d = t & 3;
        sloc[(b * K1 + k) * 4 + d] = loc[((size_t)b * P + s_order[k]) * 4 + d];
    }
    for (int t = tid; t < K1 * M; t += 1024) {
        int k = t >> 5, d = t & 31;
        smask[(b * K1 + k) * M + d] = mask[((size_t)b * P + s_order[k]) * M + d];
    }
}

// ---------------- Stage 3: 32x32 gaussians for the 100 boxes ---------------
// Computed ONCE into a 1.6 MB L2-resident buffer (R2 inlined this into the
// iou kernel -> 9x redundant exp at 4% occupancy; reverted).
__global__ void k_gauss(const float* __restrict__ sloc, float* __restrict__ gauss) {
    int bk = blockIdx.x;                    // b*K1 + k  (grid = B*K1 = 400)
    const float* l = sloc + bk * 4;
    float cx = l[0], cy = l[1];
    float sx = fabsf(l[2]) * 0.5f + 0.001f;
    float sy = fabsf(l[3]) * 0.5f + 0.001f;
    float dsx = 2.f * sx * sx;
    float dsy = 2.f * sy * sy;
    for (int p = threadIdx.x; p < G * G; p += 256) {
        int y = p >> 5, x = p & 31;
        float xs = (x + 0.5f) / (float)G;
        float ys = (y + 0.5f) / (float)G;
        float dx2 = (xs - cx) * (xs - cx) / dsx;
        float dy2 = (ys - cy) * (ys - cy) / dsy;
        gauss[(size_t)bk * (G * G) + p] = expf(-(dy2 + dx2));
    }
}

// ---------------- Stage 4a: partial inter/union per (pair-tile, chunk) -----
// block = (chunk, tilepair, b) -> 896 blocks; 256 threads = 16x16 pairs.
// Each block writes its partial sums to a PRIVATE float2 slot: no atomics,
// no memset (every slot written), deterministic chunk-sum order in 4b.
// DIRECT min/max sums (no (S-D)/(S+D) identity -- that cancellation flipped
// the rank-15 selection for near-disjoint pairs in a previous round).
__global__ __launch_bounds__(256) void k_iou_tile(
    const float* __restrict__ gauss, float2* __restrict__ pbuf) {
    int ch = blockIdx.x;
    int tp = blockIdx.y;
    int b  = blockIdx.z;
    int ti = 0, rem = tp;
    while (rem >= NT - ti) { rem -= NT - ti; ++ti; }
    int tj = ti + rem;

    __shared__ __align__(16) float As[TI][SP];
    __shared__ __align__(16) float Bs[TI][SP];

    int tid = threadIdx.x;
    for (int idx = tid; idx < TI * (CH / 4); idx += 256) {
        int g = idx >> 5, v = idx & 31;
        int gi = ti * TI + g;
        float4 f = make_float4(0.f, 0.f, 0.f, 0.f);
        if (gi < K1)
            f = *(const float4*)(gauss + ((size_t)(b * K1 + gi) << 10) + ch * CH + v * 4);
        *(float4*)(&As[g][v * 4]) = f;
        int gj = tj * TI + g;
        float4 h = make_float4(0.f, 0.f, 0.f, 0.f);
        if (gj < K1)
            h = *(const float4*)(gauss + ((size_t)(b * K1 + gj) << 10) + ch * CH + v * 4);
        *(float4*)(&Bs[g][v * 4]) = h;
    }
    __syncthreads();

    int li = tid >> 4, lj = tid & 15;
    const float4* ar = (const float4*)(&As[li][0]);
    const float4* br = (const float4*)(&Bs[lj][0]);
    float inter = 0.f, uni = 0.f;
#pragma unroll
    for (int p = 0; p < CH / 4; ++p) {
        float4 a = ar[p], c = br[p];
        inter += fminf(a.x, c.x) + fminf(a.y, c.y)
               + fminf(a.z, c.z) + fminf(a.w, c.w);
        uni   += fmaxf(a.x, c.x) + fmaxf(a.y, c.y)
               + fmaxf(a.z, c.z) + fmaxf(a.w, c.w);
    }
    pbuf[(((size_t)(b * NTP + tp)) * NCH + ch) * 256 + tid] = make_float2(inter, uni);
}

// ---------------- Stage 4b: sum chunks, iou = I/U, atomicMax per column ----
__global__ __launch_bounds__(256) void k_combine(
    const float2* __restrict__ pbuf, unsigned int* __restrict__ ioumax) {
    int tp = blockIdx.x;     // grid (NTP, B)
    int b  = blockIdx.y;
    int tid = threadIdx.x;
    int ti = 0, rem = tp;
    while (rem >= NT - ti) { rem -= NT - ti; ++ti; }
    int tj = ti + rem;
    int li = tid >> 4, lj = tid & 15;
    int i = ti * TI + li, j = tj * TI + lj;

    size_t base = ((size_t)(b * NTP + tp)) * NCH * 256 + tid;
    float I = 0.f, U = 0.f;
#pragma unroll
    for (int ch = 0; ch < NCH; ++ch) {
        float2 f = pbuf[base + (size_t)ch * 256];
        I += f.x;
        U += f.y;
    }
    if (i < j && j < K1) {
        float iou = I / U;   // > 0, so uint-compare == float-compare
        atomicMax(&ioumax[b * K1 + j], __float_as_uint(iou));
    }
}

// ---------------- Stage 5: keep-select + final_conf at 138x138 -------------
// Each block redundantly redoes the 15-smallest-iou_max selection (wave 0,
// ~700 cycles) and gathers kmask/kloc/kconf straight from smask/sloc/sconf
// -- removes the k_keep dispatch and its buffers (free: fconf blocks are
// 300-wide parallel, selection is off the critical path).
__global__ __launch_bounds__(256) void k_fconf(
    const float* __restrict__ proto, const unsigned int* __restrict__ ioumax,
    const float* __restrict__ sloc, const float* __restrict__ smask,
    const float* __restrict__ sconf, float* __restrict__ fconf) {
    int b = blockIdx.y;
    int px0 = blockIdx.x * 256;
    int tid = threadIdx.x;
    __shared__ float s_pv[256][M + 1];
    __shared__ float s_km[K2][M];
    __shared__ float s_loc[K2][4];
    __shared__ float s_cf[K2];
    __shared__ int s_keep[K2];

    if (tid < 64) {   // wave 0: stable 15-smallest selection
        int lane = tid;
        float v0 = (lane < K1)      ? __uint_as_float(ioumax[b * K1 + lane])      : INFINITY;
        float v1 = (lane + 64 < K1) ? __uint_as_float(ioumax[b * K1 + lane + 64]) : INFINITY;
        for (int k = 0; k < K2; ++k) {
            float bv; int bi;
            if (v0 <= v1) { bv = v0; bi = lane; }
            else          { bv = v1; bi = lane + 64; }
#pragma unroll
            for (int o = 32; o; o >>= 1) {
                float ov = __shfl_xor(bv, o, 64);
                int   oi = __shfl_xor(bi, o, 64);
                if (ov < bv || (ov == bv && oi < bi)) { bv = ov; bi = oi; }
            }
            if (bi == lane)           v0 = INFINITY;
            else if (bi == lane + 64) v1 = INFINITY;
            if (lane == 0) s_keep[k] = bi;
        }
    }
    __syncthreads();

    for (int t = tid; t < K2 * M; t += 256) {
        int k = t >> 5, d = t & 31;
        s_km[k][d] = smask[(b * K1 + s_keep[k]) * M + d];
    }
    for (int t = tid; t < K2 * 4; t += 256) {
        int k = t >> 2, d = t & 3;
        s_loc[k][d] = sloc[(b * K1 + s_keep[k]) * 4 + d];
    }
    if (tid < K2) s_cf[tid] = sconf[b * K1 + s_keep[tid]];

    int nvalid = min(256, HP * HP - px0);
    const float4* pr4 = (const float4*)(proto + ((size_t)b * (HP * HP) + px0) * M);
    for (int idx = tid; idx < nvalid * (M / 4); idx += 256) {
        float4 f = pr4[idx];
        int q = idx >> 3, v = idx & 7;
        s_pv[q][v * 4 + 0] = f.x;
        s_pv[q][v * 4 + 1] = f.y;
        s_pv[q][v * 4 + 2] = f.z;
        s_pv[q][v * 4 + 3] = f.w;
    }
    __syncthreads();

    if (tid < nvalid) {
        int p = px0 + tid;
        int h = p / HP, w = p % HP;
        float pv[M];
#pragma unroll
        for (int m = 0; m < M; ++m) pv[m] = s_pv[tid][m];
        float ys = (h + 0.5f) / (float)HP;
        float xs = (w + 0.5f) / (float)HP;
        float sum_a = 0.f, sum_a2 = 0.f;
#pragma unroll 1
        for (int k = 0; k < K2; ++k) {
            float d = 0.f;
#pragma unroll
            for (int m = 0; m < M; ++m) d += pv[m] * s_km[k][m];
            float sig = 1.f / (1.f + expf(-d));
            float cx = s_loc[k][0], cy = s_loc[k][1];
            float sx = fabsf(s_loc[k][2]) * 0.5f + 0.001f;
            float sy = fabsf(s_loc[k][3]) * 0.5f + 0.001f;
            float dx2 = (xs - cx) * (xs - cx) / (2.f * sx * sx);
            float dy2 = (ys - cy) * (ys - cy) / (2.f * sy * sy);
            float ug = expf(-(dy2 + dx2));
            float a = sig * ug * s_cf[k];
            sum_a  += a;
            sum_a2 += a * a;
        }
        float fin = 1.f - sum_a2 / (sum_a + FEPS);
        if (!(fin == fin)) fin = 0.f;
        fconf[(size_t)b * HP * HP + p] = fin;
    }
}

// ---------------- Stage 6: bilinear resize 138->550 fused with variance ----
// Accumulates directly into d_out (pre-zeroed by k_conf1) with /100 folded.
__global__ void k_reduce(const float* __restrict__ fconf, const float* __restrict__ original,
                         float* __restrict__ out) {
    int idx = blockIdx.x * 256 + threadIdx.x;
    float contrib = 0.f;
    if (idx < HO * HO) {
        int y = idx / HO, x = idx % HO;
        const float scale = (float)HP / (float)HO;
        float fy = (y + 0.5f) * scale - 0.5f;
        float fx = (x + 0.5f) * scale - 0.5f;
        float y0f = floorf(fy), x0f = floorf(fx);
        float wy = fy - y0f, wx = fx - x0f;
        int y0 = (int)y0f, x0 = (int)x0f;
        int iy0 = max(y0, 0), iy1 = min(y0 + 1, HP - 1);
        int ix0 = max(x0, 0), ix1 = min(x0 + 1, HP - 1);
        float r[B];
#pragma unroll
        for (int b = 0; b < B; ++b) {
            const float* F = fconf + (size_t)b * HP * HP;
            float v00 = F[iy0 * HP + ix0], v01 = F[iy0 * HP + ix1];
            float v10 = F[iy1 * HP + ix0], v11 = F[iy1 * HP + ix1];
            r[b] = (1.f - wy) * ((1.f - wx) * v00 + wx * v01)
                 +        wy  * ((1.f - wx) * v10 + wx * v11);
        }
        float t = r[0] + r[1] + r[2] + r[3];
        float s = 0.f;
#pragma unroll
        for (int c = 0; c < 3; ++c) {
            float o[B], wm = 0.f;
#pragma unroll
            for (int b = 0; b < B; ++b) {
                o[b] = original[(((size_t)b * 3 + c) * HO + y) * HO + x];
                wm += o[b] * r[b];
            }
#pragma unroll
            for (int b = 0; b < B; ++b) {
                float d = o[b] - wm;
                s += d * d * r[b];
            }
        }
        contrib = s / (t + FEPS);
    }
    __shared__ float red[256];
    red[threadIdx.x] = contrib;
    __syncthreads();
    for (int off = 128; off; off >>= 1) {
        if (threadIdx.x < off) red[threadIdx.x] += red[threadIdx.x + off];
        __syncthreads();
    }
    if (threadIdx.x == 0) atomicAdd(out, red[0] * 0.01f);
}

extern "C" void kernel_launch(void* const* d_in, const int* in_sizes, int n_in,
                              void* d_out, int out_size, void* d_ws, size_t ws_size,
                              hipStream_t stream) {
    (void)in_sizes; (void)n_in; (void)out_size; (void)ws_size;
    const float* original = (const float*)d_in[0];
    const float* loc      = (const float*)d_in[1];
    const float* conf     = (const float*)d_in[2];
    const float* mask     = (const float*)d_in[3];
    const float* proto    = (const float*)d_in[4];
    float* out = (float*)d_out;

    char* ws = (char*)d_ws;
    size_t off = 0;
    auto alloc = [&](size_t bytes) -> void* {
        void* p = ws + off;
        off += (bytes + 255) & ~(size_t)255;
        return p;
    };
    float* conf1        = (float*)alloc((size_t)B * P * sizeof(float));
    float* sconf        = (float*)alloc((size_t)B * K1 * sizeof(float));
    float* sloc         = (float*)alloc((size_t)B * K1 * 4 * sizeof(float));
    float* smask        = (float*)alloc((size_t)B * K1 * M * sizeof(float));
    float* gauss        = (float*)alloc((size_t)B * K1 * G * G * sizeof(float));
    float2* pbuf        = (float2*)alloc((size_t)B * NTP * NCH * 256 * sizeof(float2));
    unsigned int* iomax = (unsigned int*)alloc((size_t)B * K1 * sizeof(unsigned int));
    float* fconf        = (float*)alloc((size_t)B * HP * HP * sizeof(float));

    // 7 dispatches, 0 memsets. Grids sized for occupancy, not node count.
    k_conf1<<<(B * P) / 4, 256, 0, stream>>>(conf, conf1, iomax, out);
    k_top100<<<B, 1024, 0, stream>>>(conf1, loc, mask, sconf, sloc, smask);
    k_gauss<<<B * K1, 256, 0, stream>>>(sloc, gauss);
    dim3 g4(NCH, NTP, B);
    k_iou_tile<<<g4, 256, 0, stream>>>(gauss, pbuf);
    dim3 g4b(NTP, B);
    k_combine<<<g4b, 256, 0, stream>>>(pbuf, iomax);
    dim3 g6((HP * HP + 255) / 256, B);
    k_fconf<<<g6, 256, 0, stream>>>(proto, iomax, sloc, smask, sconf, fconf);
    k_reduce<<<(HO * HO + 255) / 256, 256, 0, stream>>>(fconf, original, out);
}